// Round 7
// baseline (58.163 us; speedup 1.0000x reference)
//
#include <hip/hip_runtime.h>

// B=8, L=4096, D=1024, W=128. out[b,l,d] = sort128_window( v[b,(l-d)%L,d] )
constexpr int kL   = 4096;
constexpr int kD   = 1024;
constexpr int kW   = 128;
constexpr int kDT  = 32;   // columns per block
constexpr int kNWB = 2;    // windows per block
constexpr int kROWS = kNWB * kW + kDT;  // 287 -> 288 rows
// band = 288*32*4 = 36,864 B; block = 256 threads (4 waves); 4 blocks/CU.

// Additive slot rotation: slot' = (slot + 2*(s>>4)) & 7.
// Reads: q-groups differ by s+=32 -> rot differs by 2 -> slot ranges
// {2q..2q+3} mod 8 tile the 8 slots exactly twice -> 2-way max (free, m136).
// Writes: rotation permutes whole 16B slots within a row, so each row still
// covers banks 0..31 exactly once -> staging b128 stays conflict-free.
// (R6's XOR swizzle failed both: slot^X permutes within {0..3} so q-groups
// still 4-way collide, and it broke write contiguity -> 1.16M conflicts.)
__device__ __forceinline__ int bandAddr(int s, int col) {
    const int rot = (s >> 4) & 6;
    return s * kDT + ((((col >> 2) + rot) & 7) << 2) + (col & 3);
}

// Bitonic sort / merge with all-constant indices (SROA -> registers).
template<int K, int J, int N>
__device__ __forceinline__ void bitonic_stage(float (&e)[N]) {
    #pragma unroll
    for (int i = 0; i < N; ++i) {
        const int ij = i ^ J;
        if (ij > i) {
            const bool up = ((i & K) == 0);
            const float a = e[i], c = e[ij];
            const float lo = fminf(a, c), hi = fmaxf(a, c);
            e[i]  = up ? lo : hi;
            e[ij] = up ? hi : lo;
        }
    }
    if constexpr (J > 1)      bitonic_stage<K, J / 2, N>(e);
    else if constexpr (K < N) bitonic_stage<K * 2, K, N>(e);
}

template<int J, int N>
__device__ __forceinline__ void bitonic_merge(float (&e)[N]) {
    #pragma unroll
    for (int i = 0; i < N; ++i) {
        const int ij = i ^ J;
        if (ij > i) {
            const float a = e[i], c = e[ij];
            e[i]  = fminf(a, c);
            e[ij] = fmaxf(a, c);
        }
    }
    if constexpr (J > 1) bitonic_merge<J / 2, N>(e);
}

__global__ __launch_bounds__(256, 4) void SWD20_sortwin_kernel(
    const float* __restrict__ v, float* __restrict__ out) {
    __shared__ float band[kROWS * kDT];

    const int tid = threadIdx.x;
    const int d0  = blockIdx.x * kDT;
    const int w0  = blockIdx.y * kNWB;
    const int b   = blockIdx.z;

    const size_t base = (size_t)b * kL * kD;
    const int r_lo = w0 * kW - d0 - (kDT - 1);

    // ---- stage band: 288 rows x 32 cols, float4, rotated slots (9 iters) --
    #pragma unroll
    for (int it = 0; it < (kROWS * kDT / 4) / 256; ++it) {
        const int c    = it * 256 + tid;            // float4 index
        const int s    = c >> 3;                    // band row (8 float4/row)
        const int slot = ((c & 7) + ((s >> 4) & 6)) & 7;  // rotated slot
        const int gr   = (r_lo + s + 2 * kL) & (kL - 1);
        *reinterpret_cast<float4*>(&band[s * kDT + (slot << 2)]) =
            *reinterpret_cast<const float4*>(
                v + base + (size_t)gr * kD + d0 + ((c & 7) << 2));
    }
    __syncthreads();

    // ---- 4 lanes per (window, column): lane q owns elements [32q, 32q+32) --
    const int wave = tid >> 6;
    const int wl   = wave >> 1;             // window (0..1)
    const int h    = wave & 1;              // column half (0..1)
    const int lane = tid & 63;
    const int q    = lane >> 4;             // quarter (0..3)
    const int c    = lane & 15;
    const int dl   = h * 16 + c;            // column within tile
    const int sbase = wl * kW + (kDT - 1) - dl + 32 * q;

    // Sign-domain bitonic-128 across 4 lanes (derivation in R6; unchanged).
    const float s0 = (q & 1) ? -1.f : 1.f;
    const float m1 = (q & 2) ? -1.f : 1.f;              // sigma0 -> sigmaA
    const float m2 = (q & 1) ? -1.f : 1.f;              // sigmaA -> sigmaLA
    const float m4 = (q == 1 || q == 2) ? -1.f : 1.f;   // sigmaB -> sigmaC
    const float m5 = (q & 1) ? -1.f : 1.f;              // sigmaC -> real

    float e[32];
    #pragma unroll
    for (int j = 0; j < 32; ++j)
        e[j] = band[bandAddr(sbase + j, dl)] * s0;

    bitonic_stage<2, 1, 32>(e);                         // local sort-32

    #pragma unroll
    for (int j = 0; j < 32; ++j) e[j] *= m1;
    #pragma unroll
    for (int j = 0; j < 32; ++j)                        // cross K=64 J=32
        e[j] = fminf(e[j], -__shfl_xor(e[j], 16));
    #pragma unroll
    for (int j = 0; j < 32; ++j) e[j] *= m2;
    bitonic_merge<16, 32>(e);                           // local K=64 J<=16

    #pragma unroll
    for (int j = 0; j < 32; ++j)                        // cross K=128 J=64
        e[j] = fminf(e[j], -__shfl_xor(e[j], 32));
    #pragma unroll
    for (int j = 0; j < 32; ++j) e[j] *= m4;
    #pragma unroll
    for (int j = 0; j < 32; ++j)                        // cross K=128 J=32
        e[j] = fminf(e[j], -__shfl_xor(e[j], 16));
    #pragma unroll
    for (int j = 0; j < 32; ++j) e[j] *= m5;
    bitonic_merge<16, 32>(e);                           // final local merge

    // ---- store: fixed j => 4 segments of 64B per wave.
    // Non-temporal: output never re-read; keeps v resident in L3.
    float* op = out + base +
        ((size_t)((w0 + wl) * kW + 32 * q)) * kD + d0 + dl;
    #pragma unroll
    for (int j = 0; j < 32; ++j)
        __builtin_nontemporal_store(e[j], op + (size_t)j * kD);
}

extern "C" void kernel_launch(void* const* d_in, const int* in_sizes, int n_in,
                              void* d_out, int out_size, void* d_ws, size_t ws_size,
                              hipStream_t stream) {
    const float* v = (const float*)d_in[2];   // inputs: q, k, v — only v used
    float* out = (float*)d_out;
    const int B = in_sizes[2] / (kL * kD);    // = 8
    dim3 grid(kD / kDT, (kL / kW) / kNWB, B); // 32 x 16 x 8 = 4096 blocks
    dim3 block(256);
    hipLaunchKernelGGL(SWD20_sortwin_kernel, grid, block, 0, stream, v, out);
}

// Round 8
// 56.672 us; speedup vs baseline: 1.0263x; 1.0263x over previous
//
#include <hip/hip_runtime.h>
#include <cstdint>

// B=8, L=4096, D=1024, W=128. out[b,l,d] = sort128_window( v[b,(l-d)%L,d] )
constexpr int kL    = 4096;
constexpr int kD    = 1024;
constexpr int kW    = 128;
constexpr int kDT   = 32;   // columns per block
constexpr int kNWB  = 2;    // windows per block-iteration
constexpr int kNITER= 2;    // window-groups per block (pipelined)
constexpr int kROWS = kNWB * kW + kDT;   // 287 -> 288 rows
// band = 288*32*4 = 36,864 B; block = 128 threads (2 waves); 4 blocks/CU.
// R5 structure (best: 53.8us, 0 conflicts, full-line stores) + async
// global_load_lds staging pipelined across kNITER window-groups.

// Bitonic sort / merge with all-constant indices (SROA -> registers).
template<int K, int J, int N>
__device__ __forceinline__ void bitonic_stage(float (&e)[N]) {
    #pragma unroll
    for (int i = 0; i < N; ++i) {
        const int ij = i ^ J;
        if (ij > i) {
            const bool up = ((i & K) == 0);
            const float a = e[i], c = e[ij];
            const float lo = fminf(a, c), hi = fmaxf(a, c);
            e[i]  = up ? lo : hi;
            e[ij] = up ? hi : lo;
        }
    }
    if constexpr (J > 1)      bitonic_stage<K, J / 2, N>(e);
    else if constexpr (K < N) bitonic_stage<K * 2, K, N>(e);
}

template<int J, int N>
__device__ __forceinline__ void bitonic_merge(float (&e)[N]) {
    #pragma unroll
    for (int i = 0; i < N; ++i) {
        const int ij = i ^ J;
        if (ij > i) {
            const float a = e[i], c = e[ij];
            e[i]  = fminf(a, c);
            e[ij] = fmaxf(a, c);
        }
    }
    if constexpr (J > 1) bitonic_merge<J / 2, N>(e);
}

__global__ __launch_bounds__(128, 1) void SWD20_sortwin_kernel(
    const float* __restrict__ v, float* __restrict__ out) {
    __shared__ float band[kROWS * kDT];

    const int tid = threadIdx.x;
    const int d0  = blockIdx.x * kDT;
    const int g0  = blockIdx.y * kNITER;    // first window-group of this block
    const int b   = blockIdx.z;

    const size_t base = (size_t)b * kL * kD;

    const int wl   = tid >> 6;              // window within group (0..1)
    const int lane = tid & 63;
    const int half = lane >> 5;             // 0: elems 0..63, 1: 64..127
    const int dl   = lane & 31;             // column within tile
    const int sbase = wl * kW + (kDT - 1) - dl + half * 64;
    const float sgn = half ? -1.0f : 1.0f;  // hi half sorts negated (desc)

    // async stage of one 288x32 band via direct-to-LDS loads.
    // LDS dest is wave-uniform base + lane*16 (linear float4 c = it*128+tid),
    // global source is per-lane (row wrap allowed on the source side).
    auto stage_issue = [&](int g) {
        const int r_lo = g * kNWB * kW - d0 - (kDT - 1);
        #pragma unroll
        for (int it = 0; it < (kROWS * kDT / 4) / 128; ++it) {   // 18
            const int c  = it * 128 + tid;       // float4 index
            const int s  = c >> 3;               // band row (8 float4/row)
            const int fo = (c & 7) << 2;
            const int gr = (r_lo + s + 2 * kL) & (kL - 1);
            const float* src = v + base + (size_t)gr * kD + d0 + fo;
            float* dst = &band[(it * 128 + (tid & 64)) * 4];     // wave-uniform
            __builtin_amdgcn_global_load_lds(
                (const __attribute__((address_space(1))) uint32_t*)src,
                (__attribute__((address_space(3))) uint32_t*)dst, 16, 0, 0);
        }
    };

    stage_issue(g0);
    asm volatile("s_waitcnt vmcnt(0)" ::: "memory");
    __syncthreads();

    #pragma unroll
    for (int t = 0; t < kNITER; ++t) {
        // ---- extract this thread's shifted half-window (64 ds_read_b32,
        //      bank = dl, 2 lanes/bank split across half-waves: conflict-free)
        float e[64];
        #pragma unroll
        for (int j = 0; j < 64; ++j)
            e[j] = band[(sbase + j) * kDT + dl] * sgn;

        __syncthreads();                    // all extracted; band reusable

        if (t + 1 < kNITER) stage_issue(g0 + t + 1);   // lands during sort

        // ---- sort own 64 (hi half: real-descending via sign trick) ----
        bitonic_stage<2, 1, 64>(e);
        // cross-lane stage (j=64 of the 128 network): uniform, no divergence
        #pragma unroll
        for (int j = 0; j < 64; ++j) {
            const float r = __shfl_xor(e[j], 32);
            e[j] = fminf(e[j], -r);
        }
        #pragma unroll
        for (int j = 0; j < 64; ++j) e[j] *= sgn;      // restore real values
        bitonic_merge<32, 64>(e);           // final lane-local merge

        if (t + 1 < kNITER) {
            asm volatile("s_waitcnt vmcnt(0)" ::: "memory"); // own loads done
            __syncthreads();                // band(t+1) visible to all waves
        }

        // ---- store (after barrier: overlaps next iter's extract).
        // fixed j => two contiguous 128B segments per wave; nt keeps v in L3.
        const int w0 = (g0 + t) * kNWB;
        float* op = out + base +
            ((size_t)(w0 + wl) * kW + half * 64) * kD + d0 + dl;
        #pragma unroll
        for (int j = 0; j < 64; ++j)
            __builtin_nontemporal_store(e[j], op + (size_t)j * kD);
    }
}

extern "C" void kernel_launch(void* const* d_in, const int* in_sizes, int n_in,
                              void* d_out, int out_size, void* d_ws, size_t ws_size,
                              hipStream_t stream) {
    const float* v = (const float*)d_in[2];   // inputs: q, k, v — only v used
    float* out = (float*)d_out;
    const int B = in_sizes[2] / (kL * kD);    // = 8
    // 32 x (16/kNWB/kNITER=4... ) x 8: window-groups = 16, /NITER=2 -> 8
    dim3 grid(kD / kDT, (kL / kW) / kNWB / kNITER, B);  // 32 x 8 x 8 = 2048
    dim3 block(128);
    hipLaunchKernelGGL(SWD20_sortwin_kernel, grid, block, 0, stream, v, out);
}

// Round 9
// 53.452 us; speedup vs baseline: 1.0881x; 1.0602x over previous
//
#include <hip/hip_runtime.h>
#include <cstdint>

// B=8, L=4096, D=1024, W=128. out[b,l,d] = sort128_window( v[b,(l-d)%L,d] )
constexpr int kL    = 4096;
constexpr int kD    = 1024;
constexpr int kW    = 128;
constexpr int kDT   = 32;   // columns per block
constexpr int kROWS = kW + kDT;          // 159 -> 160 rows (1 window + halo)
// band = 160*32*4 = 20,480 B; block = 64 threads (1 wave);
// 8 independent blocks/CU (LDS-capped), no barriers at all.

// Bitonic sort / merge with all-constant indices (SROA -> registers).
template<int K, int J, int N>
__device__ __forceinline__ void bitonic_stage(float (&e)[N]) {
    #pragma unroll
    for (int i = 0; i < N; ++i) {
        const int ij = i ^ J;
        if (ij > i) {
            const bool up = ((i & K) == 0);
            const float a = e[i], c = e[ij];
            const float lo = fminf(a, c), hi = fmaxf(a, c);
            e[i]  = up ? lo : hi;
            e[ij] = up ? hi : lo;
        }
    }
    if constexpr (J > 1)      bitonic_stage<K, J / 2, N>(e);
    else if constexpr (K < N) bitonic_stage<K * 2, K, N>(e);
}

template<int J, int N>
__device__ __forceinline__ void bitonic_merge(float (&e)[N]) {
    #pragma unroll
    for (int i = 0; i < N; ++i) {
        const int ij = i ^ J;
        if (ij > i) {
            const float a = e[i], c = e[ij];
            e[i]  = fminf(a, c);
            e[ij] = fmaxf(a, c);
        }
    }
    if constexpr (J > 1) bitonic_merge<J / 2, N>(e);
}

__global__ __launch_bounds__(64, 2) void SWD20_sortwin_kernel(
    const float* __restrict__ v, float* __restrict__ out) {
    __shared__ float band[kROWS * kDT];

    const int tid = threadIdx.x;            // = lane (1-wave block)
    const int d0  = blockIdx.x * kDT;
    const int w0  = blockIdx.y;             // window index
    const int b   = blockIdx.z;

    const size_t base = (size_t)b * kL * kD;
    const int r_lo = w0 * kW - d0 - (kDT - 1);

    // ---- stage band: 160 rows x 32 cols via direct-to-LDS (20 iters).
    // LDS dest is wave-uniform base (HW adds lane*16); linear layout matches
    // float4 index c = it*64 + lane. Global src is per-lane (wrapped row).
    #pragma unroll
    for (int it = 0; it < (kROWS * kDT / 4) / 64; ++it) {
        const int c  = it * 64 + tid;
        const int s  = c >> 3;               // band row (8 float4/row)
        const int fo = (c & 7) << 2;
        const int gr = (r_lo + s + 2 * kL) & (kL - 1);
        const float* src = v + base + (size_t)gr * kD + d0 + fo;
        __builtin_amdgcn_global_load_lds(
            (const __attribute__((address_space(1))) uint32_t*)src,
            (__attribute__((address_space(3))) uint32_t*)&band[it * 256],
            16, 0, 0);
    }
    // single-wave block: own vmcnt(0) makes LDS data visible; no barrier.
    asm volatile("s_waitcnt vmcnt(0)" ::: "memory");

    // ---- 2 lanes per column: lane l elems 0..63, lane l+32 elems 64..127 --
    const int half = tid >> 5;
    const int dl   = tid & 31;
    const int sbase = (kDT - 1) - dl + half * 64;
    const float sgn = half ? -1.0f : 1.0f;  // hi half sorts negated (desc)

    // extract: bank = dl, lane & lane+32 share a bank (2-way = free)
    float e[64];
    #pragma unroll
    for (int j = 0; j < 64; ++j)
        e[j] = band[(sbase + j) * kDT + dl] * sgn;

    // sort own 64 ascending in storage (hi: real-descending via sign)
    bitonic_stage<2, 1, 64>(e);
    // cross-lane stage (j=64 of the 128 network): uniform fminf, no branch
    #pragma unroll
    for (int j = 0; j < 64; ++j) {
        const float r = __shfl_xor(e[j], 32);
        e[j] = fminf(e[j], -r);
    }
    #pragma unroll
    for (int j = 0; j < 64; ++j) e[j] *= sgn;   // restore real values
    bitonic_merge<32, 64>(e);                   // final lane-local merge

    // ---- store: fixed j => two contiguous 128B segments per instr.
    // Non-temporal: output never re-read; keeps v resident in L3.
    float* op = out + base + ((size_t)w0 * kW + half * 64) * kD + d0 + dl;
    #pragma unroll
    for (int j = 0; j < 64; ++j)
        __builtin_nontemporal_store(e[j], op + (size_t)j * kD);
}

extern "C" void kernel_launch(void* const* d_in, const int* in_sizes, int n_in,
                              void* d_out, int out_size, void* d_ws, size_t ws_size,
                              hipStream_t stream) {
    const float* v = (const float*)d_in[2];   // inputs: q, k, v — only v used
    float* out = (float*)d_out;
    const int B = in_sizes[2] / (kL * kD);    // = 8
    dim3 grid(kD / kDT, kL / kW, B);          // 32 x 32 x 8 = 8192 blocks
    dim3 block(64);
    hipLaunchKernelGGL(SWD20_sortwin_kernel, grid, block, 0, stream, v, out);
}